// Round 15
// baseline (193.499 us; speedup 1.0000x reference)
//
#include <hip/hip_runtime.h>
#include <hip/hip_bf16.h>
#include <limits.h>
#include <math.h>

#define N 50000
#define E_ 800000
#define ETOT 850000          // E + N self loops
#define HH 128               // HEADS*HID
#define HEADS 8
#define HID 16
#define CLS 16
#define NEG 0.2f
#define NB ((N + 255) / 256)             // 196 scan blocks
#define GBM 64
#define GEMM_NB ((N + GBM - 1) / GBM)    // 782
#define LINK_NB ((ETOT + 255) / 256)     // 3321
#define PREP_NB ((128*128 + 255) / 256)  // 64
#define A1_NB ((N*HEADS + 255) / 256)    // 1563
#define AGG1_NPB 4                       // nodes per block (1/wave)
#define AGG1_PB (N / (AGG1_NPB))         // 12500 blocks per pass

typedef unsigned short u16;
typedef unsigned int   u32;
typedef short s8v __attribute__((ext_vector_type(8)));
typedef float f4v __attribute__((ext_vector_type(4)));

__device__ __forceinline__ u16 f2bu(float f){           // f32 -> bf16 RNE
  union{float f; u32 i;} c; c.f = f;
  u32 lsb = (c.i >> 16) & 1u;
  c.i += 0x7fffu + lsb;
  return (u16)(c.i >> 16);
}
__device__ __forceinline__ float bu2f(u16 u){
  union{u32 i; float f;} c; c.i = ((u32)u) << 16; return c.f;
}
__device__ __forceinline__ float blo(u32 u){ union{u32 i; float f;} c; c.i = u << 16; return c.f; }
__device__ __forceinline__ float bhi(u32 u){ union{u32 i; float f;} c; c.i = u & 0xffff0000u; return c.f; }

// ---------------- head init (replaces pathologically slow rocclr fill) ----------------
__global__ __launch_bounds__(256) void k_init(int* __restrict__ head){
  int i = blockIdx.x*256 + threadIdx.x;
  if(i < N) head[i] = -1;
}

// ---------------- fused (LDS-free): linked-list CSR build ∥ W1/W2 pre-split ----------------
__global__ __launch_bounds__(256) void k_linkprep(const int* __restrict__ ei,
                                                  int* __restrict__ head,
                                                  int* __restrict__ srcv,
                                                  int* __restrict__ nxt,
                                                  const float* __restrict__ W1,
                                                  const float* __restrict__ W2,
                                                  u16* __restrict__ wth, u16* __restrict__ wtl,
                                                  u16* __restrict__ w2th, u16* __restrict__ w2tl){
  if(blockIdx.x < PREP_NB){
    int i = blockIdx.x*256 + threadIdx.x;
    if(i < 128*128){
      int k = i >> 7, c = i & 127;
      float v = W1[i];                   // W1[k][c]
      u16 hi = f2bu(v);
      wth[c*128 + k] = hi;
      wtl[c*128 + k] = f2bu(v - bu2f(hi));
    }
    if(i < 128*16){
      int k = i >> 4, c = i & 15;
      float v = W2[i];                   // W2[k][c]
      u16 hi = f2bu(v);
      w2th[c*128 + k] = hi;
      w2tl[c*128 + k] = f2bu(v - bu2f(hi));
    }
    return;
  }
  int e = (blockIdx.x - PREP_NB)*256 + threadIdx.x;
  if(e >= ETOT) return;
  int s, d;
  if(e < E_){ s = ei[e]; d = ei[E_ + e]; } else { s = d = e - E_; }
  int old = atomicExch(&head[d], e);
  srcv[e] = s;
  nxt[e]  = old;
}

// ---------------- fused: MFMA split-bf16 GEMM1 ∥ degree list-walk + block sums ----------------
// h1 output layout: slice-major h1hm[c>>5][node][c&31] (4 slices of 32ch, 3.2MB each)
__global__ __launch_bounds__(256) void k_gemm1walk(const float* __restrict__ x,
                                                   const u16* __restrict__ wth,
                                                   const u16* __restrict__ wtl,
                                                   u16* __restrict__ h1hm,
                                                   const int* __restrict__ head,
                                                   const int* __restrict__ nxt,
                                                   int* __restrict__ deg,
                                                   int* __restrict__ bsum){
  __shared__ u16 xh[GBM][40], xl[GBM][40];     // pad-40: 2-way bank alias (free)
  __shared__ u16 wh[128][40], wl[128][40];
  __shared__ int sm[256];
  if(blockIdx.x >= GEMM_NB){
    int b = blockIdx.x - GEMM_NB;              // 0..NB-1
    int t = threadIdx.x;
    int i = b*256 + t;
    int cnt = 0;
    if(i < N){
      int e = head[i];
      while(e >= 0){ cnt++; e = nxt[e]; }
      deg[i] = cnt;
    }
    sm[t] = cnt;
    __syncthreads();
    #pragma unroll
    for(int ofs=128; ofs>0; ofs>>=1){
      if(t < ofs) sm[t] += sm[t+ofs];
      __syncthreads();
    }
    if(t == 0) bsum[b] = sm[0];
    return;
  }
  int tid  = threadIdx.x;
  int wv   = tid >> 6;
  int lane = tid & 63;
  int row0 = blockIdx.x * GBM;

  f4v acc[4][2];
  #pragma unroll
  for(int t=0;t<4;t++)
    #pragma unroll
    for(int u=0;u<2;u++) acc[t][u] = (f4v){0.f,0.f,0.f,0.f};

  int xr  = tid >> 2;
  int xkq = (tid & 3) * 8;
  int wc  = tid & 127;
  int wq  = (tid >> 7) * 8;
  int xrow = row0 + xr; if(xrow >= N) xrow = N-1;
  const float* xb = x + (size_t)xrow*128 + xkq;
  int fr = lane & 15, fg = lane >> 4;
  int kk = fg*8;

  for(int kc=0; kc<4; kc++){
    int k0 = kc*32;
    float4 v0 = *(const float4*)(xb + k0);
    float4 v1 = *(const float4*)(xb + k0 + 4);
    __syncthreads();
    {
      float vv[8] = {v0.x,v0.y,v0.z,v0.w,v1.x,v1.y,v1.z,v1.w};
      s8v H, L;
      #pragma unroll
      for(int j=0;j<8;j++){
        u16 h_ = f2bu(vv[j]);
        H[j] = (short)h_;
        L[j] = (short)f2bu(vv[j] - bu2f(h_));
      }
      *(s8v*)&xh[xr][xkq] = H;
      *(s8v*)&xl[xr][xkq] = L;
    }
    #pragma unroll
    for(int j=0;j<2;j++){
      int kq = wq + j*16;
      *(s8v*)&wh[wc][kq] = *(const s8v*)&wth[wc*128 + k0 + kq];
      *(s8v*)&wl[wc][kq] = *(const s8v*)&wtl[wc*128 + k0 + kq];
    }
    __syncthreads();
    s8v a_h[4], a_l[4], b_h[2], b_l[2];
    #pragma unroll
    for(int t=0;t<4;t++){
      a_h[t] = *(const s8v*)&xh[t*16 + fr][kk];
      a_l[t] = *(const s8v*)&xl[t*16 + fr][kk];
    }
    #pragma unroll
    for(int u=0;u<2;u++){
      int col = wv*32 + u*16 + fr;
      b_h[u] = *(const s8v*)&wh[col][kk];
      b_l[u] = *(const s8v*)&wl[col][kk];
    }
    #pragma unroll
    for(int t=0;t<4;t++){
      #pragma unroll
      for(int u=0;u<2;u++){
        acc[t][u] = __builtin_amdgcn_mfma_f32_16x16x32_bf16(a_h[t], b_h[u], acc[t][u], 0,0,0);
        acc[t][u] = __builtin_amdgcn_mfma_f32_16x16x32_bf16(a_h[t], b_l[u], acc[t][u], 0,0,0);
        acc[t][u] = __builtin_amdgcn_mfma_f32_16x16x32_bf16(a_l[t], b_h[u], acc[t][u], 0,0,0);
      }
    }
  }
  // D layout: row = t*16 + fg*4 + j, col = wv*32 + u*16 + fr
  // write slice-major: addr(c0,row) = ((c0>>5)*N + row)*32 + (c0&31)
  #pragma unroll
  for(int t=0;t<4;t++){
    #pragma unroll
    for(int j=0;j<4;j++){
      int row = row0 + t*16 + fg*4 + j;
      if(row < N){
        int c0 = wv*32 + fr;         // acc[t][0] -> col c0, acc[t][1] -> col c0+16
        u16* d0 = h1hm + (size_t)((c0>>5)*N + row)*32 + (c0&31);
        d0[0]  = f2bu(acc[t][0][j]);
        d0[16] = f2bu(acc[t][1][j]);  // c0+16 same slice (fr<16)
      }
    }
  }
}

// ---------------- fused: scan3 + list-walk CSR fill ∥ alpha1 (head-major as/ad) ----------------
__global__ __launch_bounds__(256) void k_scan3alpha(const int* __restrict__ deg,
                                                    const int* __restrict__ bsum,
                                                    const int* __restrict__ head,
                                                    const int* __restrict__ srcv,
                                                    const int* __restrict__ nxt,
                                                    int* __restrict__ off,
                                                    int* __restrict__ csr,
                                                    const u16* __restrict__ h1hm,
                                                    const float* __restrict__ Asv,
                                                    const float* __restrict__ Adv,
                                                    float* __restrict__ as1,
                                                    float* __restrict__ ad1){
  __shared__ int red[256];
  __shared__ int sm[256];
  if(blockIdx.x < NB){
    int t = threadIdx.x;
    red[t] = (t < blockIdx.x) ? bsum[t] : 0;   // blockIdx.x <= 195 < 256
    __syncthreads();
    #pragma unroll
    for(int ofs=128; ofs>0; ofs>>=1){
      if(t < ofs) red[t] += red[t+ofs];
      __syncthreads();
    }
    int boff = red[0];
    int i = blockIdx.x*256 + t;
    int v0 = (i < N) ? deg[i] : 0;
    sm[t] = v0;
    __syncthreads();
    #pragma unroll
    for(int ofs=1; ofs<256; ofs<<=1){
      int v = sm[t];
      int add = (t >= ofs) ? sm[t-ofs] : 0;
      __syncthreads();
      sm[t] = v + add;
      __syncthreads();
    }
    if(i < N){
      int excl = boff + sm[t] - v0;
      off[i] = excl;
      if(i == N-1) off[N] = excl + v0;
      int e = head[i];
      int pos = excl;
      while(e >= 0){
        csr[pos++] = srcv[e];
        e = nxt[e];
      }
    }
    return;
  }
  int id = (blockIdx.x - NB)*256 + threadIdx.x;
  if(id >= N*HEADS) return;
  int i = id >> 3, h = id & 7;
  const uint4* hv = (const uint4*)(h1hm + (size_t)((h>>1)*N + i)*32 + (h&1)*16);
  uint4 u0 = hv[0], u1 = hv[1];
  float vals[16] = {blo(u0.x),bhi(u0.x),blo(u0.y),bhi(u0.y),
                    blo(u0.z),bhi(u0.z),blo(u0.w),bhi(u0.w),
                    blo(u1.x),bhi(u1.x),blo(u1.y),bhi(u1.y),
                    blo(u1.z),bhi(u1.z),blo(u1.w),bhi(u1.w)};
  float s=0.f, d=0.f;
  #pragma unroll
  for(int j=0;j<16;j++){
    s = fmaf(vals[j], Asv[h*HID+j], s);
    d = fmaf(vals[j], Adv[h*HID+j], d);
  }
  as1[(size_t)h*N + i] = s;            // head-major: L2-resident 200KB slices
  ad1[(size_t)h*N + i] = d;
}

// ---------------- layer-1 aggregation: 4 channel-slice passes (L2-resident slices) ----------------
// pass p = blockIdx/12500 covers channels [32p,32p+32); 1 wave per node;
// lane = (edge-quad eq = lane>>4) x (u32 channel cq = lane&15); reduce over eq via shfl.
#define CH 32
__global__ __launch_bounds__(256) void k_agg1(const int* __restrict__ off,
                                              const int* __restrict__ csr,
                                              const float* __restrict__ as1,
                                              const float* __restrict__ ad1,
                                              const u32* __restrict__ h1w,
                                              const float* __restrict__ b1,
                                              u32* __restrict__ helu_w){
  __shared__ float wsm[4][CH*2];
  __shared__ int   ssm[4][CH];
  int p    = blockIdx.x / AGG1_PB;               // pass 0..3
  int blk  = blockIdx.x % AGG1_PB;
  int wv   = threadIdx.x >> 6;
  int lane = threadIdx.x & 63;
  int node = blk*4 + wv;
  int beg = off[node], end = off[node+1];
  int ea  = lane & 31;                           // phase-A edge slot
  int hh2 = lane >> 5;                           // phase-A head half
  int headA = 2*p + hh2;
  int cq = lane & 15;                            // u32 channel in slice
  int eq = lane >> 4;                            // edge quad slot 0..3
  int hsel = cq >> 3;                            // head half for my channels
  float advA = ad1[(size_t)headA*N + node];
  float den = 0.f, num0 = 0.f, num1 = 0.f;
  float* wsw = wsm[wv];
  int*   ssw = ssm[wv];
  const u32* hp = h1w + (size_t)p*N*16;          // slice base
  const float* asp = as1 + (size_t)headA*N;
  for(int base = beg; base < end; base += CH){
    int cnt = end - base; if(cnt > CH) cnt = CH;
    if(ea < cnt){
      int s = csr[base+ea];
      if(hh2 == 0) ssw[ea] = s;
      float v = asp[s] + advA;
      v = v > 0.f ? v : NEG*v;
      wsw[ea*2+hh2] = __expf(v);       // shift-invariant softmax; logits bounded
    }
    int q = 0;
    for(; q+8 <= cnt; q += 8){
      int qa = q+eq, qb = q+4+eq;
      int sa = ssw[qa], sb = ssw[qb];
      float wa = wsw[qa*2+hsel], wb = wsw[qb*2+hsel];
      u32 ua = hp[(size_t)sa*16 + cq];
      u32 ub = hp[(size_t)sb*16 + cq];
      den += wa + wb;
      num0 = fmaf(wa, blo(ua), num0); num1 = fmaf(wa, bhi(ua), num1);
      num0 = fmaf(wb, blo(ub), num0); num1 = fmaf(wb, bhi(ub), num1);
    }
    for(; q < cnt; q += 4){
      int qa = q + eq;
      if(qa < cnt){
        int sa = ssw[qa];
        float wa = wsw[qa*2+hsel];
        u32 ua = hp[(size_t)sa*16 + cq];
        den += wa;
        num0 = fmaf(wa, blo(ua), num0);
        num1 = fmaf(wa, bhi(ua), num1);
      }
    }
  }
  // reduce across the 4 edge-quad groups (exact linear merge)
  num0 += __shfl_xor(num0,16); num0 += __shfl_xor(num0,32);
  num1 += __shfl_xor(num1,16); num1 += __shfl_xor(num1,32);
  den  += __shfl_xor(den,16);  den  += __shfl_xor(den,32);
  if(eq == 0){
    float2 bb = ((const float2*)b1)[p*16 + cq];
    float inv = 1.f / (den + 1e-16f);
    float r0 = num0*inv + bb.x;
    float r1 = num1*inv + bb.y;
    r0 = r0 > 0.f ? r0 : expm1f(r0);
    r1 = r1 > 0.f ? r1 : expm1f(r1);
    helu_w[(size_t)(p*N + node)*16 + cq] = (u32)f2bu(r0) | ((u32)f2bu(r1) << 16);
  }
}

// ---------------- MFMA GEMM2: h2[N,16] = helu(bf16, slice-major) @ W2 + fused alpha2 ----------------
__global__ __launch_bounds__(256) void k_gemm2m(const u16* __restrict__ helu,
                                                const u16* __restrict__ w2th,
                                                const u16* __restrict__ w2tl,
                                                const float* __restrict__ Asv,
                                                const float* __restrict__ Adv,
                                                u16* __restrict__ h2b,
                                                float* __restrict__ as2,
                                                float* __restrict__ ad2){
  __shared__ u16 At[4][16][136];     // per-wave A tile
  __shared__ u16 Bh[16][136], Bl[16][136];
  int tid  = threadIdx.x;
  int wv   = tid >> 6;
  int lane = tid & 63;
  int fr = lane & 15, fg = lane >> 4;
  int row0 = blockIdx.x*64 + wv*16;

  {
    int r = tid >> 4, c8 = (tid & 15)*8;
    *(s8v*)&Bh[r][c8] = *(const s8v*)&w2th[r*128 + c8];
    *(s8v*)&Bl[r][c8] = *(const s8v*)&w2tl[r*128 + c8];
  }
  #pragma unroll
  for(int j=0;j<4;j++){
    int rl = j*4 + (lane >> 4);
    int rg = row0 + rl; if(rg >= N) rg = N-1;
    int c0 = (lane & 15)*8;          // original channel block
    *(s8v*)&At[wv][rl][c0] = *(const s8v*)&helu[(size_t)((c0>>5)*N + rg)*32 + (c0&31)];
  }
  __syncthreads();

  f4v acc = (f4v){0.f,0.f,0.f,0.f};
  #pragma unroll
  for(int kc=0; kc<4; kc++){
    int kk = kc*32 + fg*8;
    s8v a  = *(const s8v*)&At[wv][fr][kk];
    s8v bh = *(const s8v*)&Bh[fr][kk];
    s8v bl = *(const s8v*)&Bl[fr][kk];
    acc = __builtin_amdgcn_mfma_f32_16x16x32_bf16(a, bh, acc, 0,0,0);
    acc = __builtin_amdgcn_mfma_f32_16x16x32_bf16(a, bl, acc, 0,0,0);
  }
  float asv = Asv[fr], adv = Adv[fr];
  #pragma unroll
  for(int j=0;j<4;j++){
    int row = row0 + fg*4 + j;
    float ps = acc[j]*asv, pd = acc[j]*adv;
    ps += __shfl_xor(ps,1); ps += __shfl_xor(ps,2); ps += __shfl_xor(ps,4); ps += __shfl_xor(ps,8);
    pd += __shfl_xor(pd,1); pd += __shfl_xor(pd,2); pd += __shfl_xor(pd,4); pd += __shfl_xor(pd,8);
    if(row < N){
      h2b[(size_t)row*16 + fr] = f2bu(acc[j]);
      if(fr == 0){ as2[row] = ps; ad2[row] = pd; }
    }
  }
}

// ---------------- fused layer-2 aggregation: 8 lanes/node, batched loads ----------------
__global__ __launch_bounds__(256) void k_agg2(const int* __restrict__ off,
                                              const int* __restrict__ csr,
                                              const float* __restrict__ as2,
                                              const float* __restrict__ ad2,
                                              const u32* __restrict__ h2w,
                                              const float* __restrict__ b2,
                                              float* __restrict__ outp){
  int t = threadIdx.x;
  int node = blockIdx.x*32 + (t >> 3);
  int c2 = t & 7;                        // channels 2*c2, 2*c2+1
  if(node >= N) return;
  int beg = off[node], end = off[node+1];
  float adv = ad2[node];
  float den = 0.f, num0 = 0.f, num1 = 0.f;
  int gbase = t & 56;
  for(int base = beg; base < end; base += 8){
    int cnt = end - base; if(cnt > 8) cnt = 8;
    float w_my = 0.f; int s_my = 0;
    if(c2 < cnt){
      s_my = csr[base + c2];
      float v = as2[s_my] + adv;
      v = v > 0.f ? v : NEG*v;
      w_my = __expf(v);
    }
    float ww[8]; int ss[8]; u32 uu[8];
    #pragma unroll
    for(int j=0;j<8;j++){
      ww[j] = __shfl(w_my, gbase | j);
      ss[j] = __shfl(s_my, gbase | j);
    }
    #pragma unroll
    for(int j=0;j<8;j++){
      if(j < cnt) uu[j] = h2w[(size_t)ss[j]*8 + c2];
    }
    #pragma unroll
    for(int j=0;j<8;j++){
      if(j < cnt){
        den += ww[j];
        num0 = fmaf(ww[j], blo(uu[j]), num0);
        num1 = fmaf(ww[j], bhi(uu[j]), num1);
      }
    }
  }
  float inv = 1.f / (den + 1e-16f);
  float2 bb = ((const float2*)b2)[c2];
  float2 r;
  r.x = num0*inv + bb.x;
  r.y = num1*inv + bb.y;
  ((float2*)outp)[(size_t)node*8 + c2] = r;
}

extern "C" void kernel_launch(void* const* d_in, const int* in_sizes, int n_in,
                              void* d_out, int out_size, void* d_ws, size_t ws_size,
                              hipStream_t stream){
  const float* x     = (const float*)d_in[0];
  const int*   ei    = (const int*)  d_in[1];
  const float* W1    = (const float*)d_in[2];
  const float* av_s1 = (const float*)d_in[3];
  const float* av_d1 = (const float*)d_in[4];
  const float* b1    = (const float*)d_in[5];
  const float* W2    = (const float*)d_in[6];
  const float* av_s2 = (const float*)d_in[7];
  const float* av_d2 = (const float*)d_in[8];
  const float* b2    = (const float*)d_in[9];
  float* outp = (float*)d_out;

  char* p = (char*)d_ws;
  auto alloc = [&](size_t bytes){ char* q = p; p += (bytes + 255) & ~(size_t)255; return q; };
  u16*   h1b    = (u16*)  alloc((size_t)N*HH*2);
  u16*   helu_b = (u16*)  alloc((size_t)N*HH*2);
  u16*   h2b    = (u16*)  alloc((size_t)N*CLS*2);
  float* as1    = (float*)alloc((size_t)N*HEADS*4);
  float* ad1    = (float*)alloc((size_t)N*HEADS*4);
  float* as2    = (float*)alloc((size_t)N*4);
  float* ad2    = (float*)alloc((size_t)N*4);
  int*   deg    = (int*)  alloc((size_t)N*4);
  int*   head   = (int*)  alloc((size_t)N*4);
  int*   off    = (int*)  alloc((size_t)(N+1)*4);
  int*   csr    = (int*)  alloc((size_t)ETOT*4);
  int*   srcv   = (int*)  alloc((size_t)ETOT*4);
  int*   nxt    = (int*)  alloc((size_t)ETOT*4);
  u16*   wth    = (u16*)  alloc((size_t)128*128*2);
  u16*   wtl    = (u16*)  alloc((size_t)128*128*2);
  u16*   w2th   = (u16*)  alloc((size_t)16*128*2);
  u16*   w2tl   = (u16*)  alloc((size_t)16*128*2);
  int*   bsum   = (int*)  alloc((size_t)NB*4);

  // custom head init (rocclr fillBuffer was 44 µs on the critical path)
  k_init<<<NB, 256, 0, stream>>>(head);

  // LDS-free: linked-list build ∥ W pre-split (full occupancy for atomics)
  k_linkprep<<<PREP_NB + LINK_NB, 256, 0, stream>>>(ei, head, srcv, nxt,
                                                    W1, W2, wth, wtl, w2th, w2tl);

  // MFMA GEMM1 (slice-major h1) ∥ degree walk + block sums
  k_gemm1walk<<<GEMM_NB + NB, 256, 0, stream>>>(x, wth, wtl, h1b, head, nxt, deg, bsum);

  // CSR offsets + walk-fill ∥ alpha1 (head-major as1/ad1)
  k_scan3alpha<<<NB + A1_NB, 256, 0, stream>>>(deg, bsum, head, srcv, nxt, off, csr,
                                               h1b, av_s1, av_d1, as1, ad1);

  // layer 1 aggregation: 4 L2-resident channel-slice passes
  k_agg1<<<4*AGG1_PB, 256, 0, stream>>>(off, csr, as1, ad1, (const u32*)h1b, b1, (u32*)helu_b);

  // layer 2
  k_gemm2m<<<(N+63)/64, 256, 0, stream>>>(helu_b, w2th, w2tl, av_s2, av_d2, h2b, as2, ad2);
  k_agg2<<<(N+31)/32, 256, 0, stream>>>(off, csr, as2, ad2, (const u32*)h2b, b2, outp);
}

// Round 16
// 145.633 us; speedup vs baseline: 1.3287x; 1.3287x over previous
//
#include <hip/hip_runtime.h>
#include <hip/hip_bf16.h>
#include <limits.h>
#include <math.h>

#define N 50000
#define E_ 800000
#define ETOT 850000          // E + N self loops
#define HH 128               // HEADS*HID
#define HEADS 8
#define HID 16
#define CLS 16
#define NEG 0.2f
#define NB ((N + 255) / 256)             // 196 scan blocks
#define GBM 64
#define GEMM_NB ((N + GBM - 1) / GBM)    // 782
#define LINK_NB ((ETOT + 255) / 256)     // 3321
#define PREP_NB ((128*128 + 255) / 256)  // 64
#define A1_NB ((N*HEADS + 255) / 256)    // 1563

typedef unsigned short u16;
typedef unsigned int   u32;
typedef unsigned long long u64;
typedef short s8v __attribute__((ext_vector_type(8)));
typedef float f4v __attribute__((ext_vector_type(4)));

__device__ __forceinline__ u16 f2bu(float f){           // f32 -> bf16 RNE
  union{float f; u32 i;} c; c.f = f;
  u32 lsb = (c.i >> 16) & 1u;
  c.i += 0x7fffu + lsb;
  return (u16)(c.i >> 16);
}
__device__ __forceinline__ float bu2f(u16 u){
  union{u32 i; float f;} c; c.i = ((u32)u) << 16; return c.f;
}
__device__ __forceinline__ float blo(u32 u){ union{u32 i; float f;} c; c.i = u << 16; return c.f; }
__device__ __forceinline__ float bhi(u32 u){ union{u32 i; float f;} c; c.i = u & 0xffff0000u; return c.f; }

// ---------------- head init (replaces pathologically slow rocclr fill) ----------------
__global__ __launch_bounds__(256) void k_init(int* __restrict__ head){
  int i = blockIdx.x*256 + threadIdx.x;
  if(i < N) head[i] = -1;
}

// ---------------- fused (LDS-free): linked-list CSR build ∥ W1/W2 pre-split ----------------
// nsrc packs (src << 32 | next): fill-walk reads ONE random line per edge, not two.
__global__ __launch_bounds__(256) void k_linkprep(const int* __restrict__ ei,
                                                  int* __restrict__ head,
                                                  u64* __restrict__ nsrc,
                                                  const float* __restrict__ W1,
                                                  const float* __restrict__ W2,
                                                  u16* __restrict__ wth, u16* __restrict__ wtl,
                                                  u16* __restrict__ w2th, u16* __restrict__ w2tl){
  if(blockIdx.x < PREP_NB){
    int i = blockIdx.x*256 + threadIdx.x;
    if(i < 128*128){
      int k = i >> 7, c = i & 127;
      float v = W1[i];                   // W1[k][c]
      u16 hi = f2bu(v);
      wth[c*128 + k] = hi;
      wtl[c*128 + k] = f2bu(v - bu2f(hi));
    }
    if(i < 128*16){
      int k = i >> 4, c = i & 15;
      float v = W2[i];                   // W2[k][c]
      u16 hi = f2bu(v);
      w2th[c*128 + k] = hi;
      w2tl[c*128 + k] = f2bu(v - bu2f(hi));
    }
    return;
  }
  int e = (blockIdx.x - PREP_NB)*256 + threadIdx.x;
  if(e >= ETOT) return;
  int s, d;
  if(e < E_){ s = ei[e]; d = ei[E_ + e]; } else { s = d = e - E_; }
  int old = atomicExch(&head[d], e);
  nsrc[e] = ((u64)(u32)s << 32) | (u32)old;
}

// ---------------- fused: MFMA split-bf16 GEMM1 ∥ degree list-walk + block sums ----------------
__global__ __launch_bounds__(256) void k_gemm1walk(const float* __restrict__ x,
                                                   const u16* __restrict__ wth,
                                                   const u16* __restrict__ wtl,
                                                   u16* __restrict__ h1b,
                                                   const int* __restrict__ head,
                                                   const u64* __restrict__ nsrc,
                                                   int* __restrict__ deg,
                                                   int* __restrict__ bsum){
  __shared__ u16 xh[GBM][40], xl[GBM][40];     // pad-40: 2-way bank alias (free)
  __shared__ u16 wh[128][40], wl[128][40];
  __shared__ int sm[256];
  if(blockIdx.x >= GEMM_NB){
    int b = blockIdx.x - GEMM_NB;              // 0..NB-1
    int t = threadIdx.x;
    int i = b*256 + t;
    int cnt = 0;
    if(i < N){
      int e = head[i];
      while(e >= 0){ cnt++; e = (int)(u32)(nsrc[e] & 0xffffffffu); }
      deg[i] = cnt;
    }
    sm[t] = cnt;
    __syncthreads();
    #pragma unroll
    for(int ofs=128; ofs>0; ofs>>=1){
      if(t < ofs) sm[t] += sm[t+ofs];
      __syncthreads();
    }
    if(t == 0) bsum[b] = sm[0];
    return;
  }
  int tid  = threadIdx.x;
  int wv   = tid >> 6;
  int lane = tid & 63;
  int row0 = blockIdx.x * GBM;

  f4v acc[4][2];
  #pragma unroll
  for(int t=0;t<4;t++)
    #pragma unroll
    for(int u=0;u<2;u++) acc[t][u] = (f4v){0.f,0.f,0.f,0.f};

  int xr  = tid >> 2;
  int xkq = (tid & 3) * 8;
  int wc  = tid & 127;
  int wq  = (tid >> 7) * 8;
  int xrow = row0 + xr; if(xrow >= N) xrow = N-1;
  const float* xb = x + (size_t)xrow*128 + xkq;
  int fr = lane & 15, fg = lane >> 4;
  int kk = fg*8;

  for(int kc=0; kc<4; kc++){
    int k0 = kc*32;
    float4 v0 = *(const float4*)(xb + k0);
    float4 v1 = *(const float4*)(xb + k0 + 4);
    __syncthreads();
    {
      float vv[8] = {v0.x,v0.y,v0.z,v0.w,v1.x,v1.y,v1.z,v1.w};
      s8v H, L;
      #pragma unroll
      for(int j=0;j<8;j++){
        u16 h_ = f2bu(vv[j]);
        H[j] = (short)h_;
        L[j] = (short)f2bu(vv[j] - bu2f(h_));
      }
      *(s8v*)&xh[xr][xkq] = H;
      *(s8v*)&xl[xr][xkq] = L;
    }
    #pragma unroll
    for(int j=0;j<2;j++){
      int kq = wq + j*16;
      *(s8v*)&wh[wc][kq] = *(const s8v*)&wth[wc*128 + k0 + kq];
      *(s8v*)&wl[wc][kq] = *(const s8v*)&wtl[wc*128 + k0 + kq];
    }
    __syncthreads();
    s8v a_h[4], a_l[4], b_h[2], b_l[2];
    #pragma unroll
    for(int t=0;t<4;t++){
      a_h[t] = *(const s8v*)&xh[t*16 + fr][kk];
      a_l[t] = *(const s8v*)&xl[t*16 + fr][kk];
    }
    #pragma unroll
    for(int u=0;u<2;u++){
      int col = wv*32 + u*16 + fr;
      b_h[u] = *(const s8v*)&wh[col][kk];
      b_l[u] = *(const s8v*)&wl[col][kk];
    }
    #pragma unroll
    for(int t=0;t<4;t++){
      #pragma unroll
      for(int u=0;u<2;u++){
        acc[t][u] = __builtin_amdgcn_mfma_f32_16x16x32_bf16(a_h[t], b_h[u], acc[t][u], 0,0,0);
        acc[t][u] = __builtin_amdgcn_mfma_f32_16x16x32_bf16(a_h[t], b_l[u], acc[t][u], 0,0,0);
        acc[t][u] = __builtin_amdgcn_mfma_f32_16x16x32_bf16(a_l[t], b_h[u], acc[t][u], 0,0,0);
      }
    }
  }
  // D layout: row = t*16 + fg*4 + j, col = wv*32 + u*16 + fr
  #pragma unroll
  for(int t=0;t<4;t++){
    #pragma unroll
    for(int j=0;j<4;j++){
      int row = row0 + t*16 + fg*4 + j;
      if(row < N){
        u16* dst = h1b + (size_t)row*128 + wv*32 + fr;
        dst[0]  = f2bu(acc[t][0][j]);
        dst[16] = f2bu(acc[t][1][j]);
      }
    }
  }
}

// ---------------- fused: scan3 + list-walk CSR fill ∥ alpha1 ----------------
__global__ __launch_bounds__(256) void k_scan3alpha(const int* __restrict__ deg,
                                                    const int* __restrict__ bsum,
                                                    const int* __restrict__ head,
                                                    const u64* __restrict__ nsrc,
                                                    int* __restrict__ off,
                                                    int* __restrict__ csr,
                                                    const u16* __restrict__ h1b,
                                                    const float* __restrict__ Asv,
                                                    const float* __restrict__ Adv,
                                                    float* __restrict__ as1,
                                                    float* __restrict__ ad1){
  __shared__ int red[256];
  __shared__ int sm[256];
  if(blockIdx.x < NB){
    int t = threadIdx.x;
    red[t] = (t < blockIdx.x) ? bsum[t] : 0;   // blockIdx.x <= 195 < 256
    __syncthreads();
    #pragma unroll
    for(int ofs=128; ofs>0; ofs>>=1){
      if(t < ofs) red[t] += red[t+ofs];
      __syncthreads();
    }
    int boff = red[0];
    int i = blockIdx.x*256 + t;
    int v0 = (i < N) ? deg[i] : 0;
    sm[t] = v0;
    __syncthreads();
    #pragma unroll
    for(int ofs=1; ofs<256; ofs<<=1){
      int v = sm[t];
      int add = (t >= ofs) ? sm[t-ofs] : 0;
      __syncthreads();
      sm[t] = v + add;
      __syncthreads();
    }
    if(i < N){
      int excl = boff + sm[t] - v0;
      off[i] = excl;
      if(i == N-1) off[N] = excl + v0;
      int e = head[i];
      int pos = excl;
      while(e >= 0){
        u64 v = nsrc[e];
        csr[pos++] = (int)(v >> 32);
        e = (int)(u32)(v & 0xffffffffu);
      }
    }
    return;
  }
  int id = (blockIdx.x - NB)*256 + threadIdx.x;
  if(id >= N*HEADS) return;
  int i = id >> 3, h = id & 7;
  const uint4* hv = (const uint4*)(h1b + (size_t)i*HH + h*HID);
  uint4 u0 = hv[0], u1 = hv[1];
  float vals[16] = {blo(u0.x),bhi(u0.x),blo(u0.y),bhi(u0.y),
                    blo(u0.z),bhi(u0.z),blo(u0.w),bhi(u0.w),
                    blo(u1.x),bhi(u1.x),blo(u1.y),bhi(u1.y),
                    blo(u1.z),bhi(u1.z),blo(u1.w),bhi(u1.w)};
  float s=0.f, d=0.f;
  #pragma unroll
  for(int j=0;j<16;j++){
    s = fmaf(vals[j], Asv[h*HID+j], s);
    d = fmaf(vals[j], Adv[h*HID+j], d);
  }
  as1[id]=s; ad1[id]=d;
}

// ---------------- fused layer-1 aggregation: 1 wave/node, CH=32, 8-deep gathers ----------------
#define CH 32
__global__ __launch_bounds__(256) void k_agg1(const int* __restrict__ off,
                                              const int* __restrict__ csr,
                                              const float* __restrict__ as1,
                                              const float* __restrict__ ad1,
                                              const u32* __restrict__ h1w,
                                              const float* __restrict__ b1,
                                              u32* __restrict__ helu_w){
  __shared__ float wsm[4][CH*8];
  __shared__ int   ssm[4][CH];
  int wv   = threadIdx.x >> 6;
  int lane = threadIdx.x & 63;
  int node = blockIdx.x*4 + wv;          // grid = N/4 exactly
  int beg = off[node], end = off[node+1];
  int h  = lane >> 3;                    // head (channels 2*lane, 2*lane+1)
  int hh = lane & 7;                     // phase-A head
  int el = lane >> 3;                    // phase-A edge slot
  float advA = ad1[node*8 + hh];
  float den = 0.f, num0 = 0.f, num1 = 0.f;
  float* wsw = wsm[wv];
  int*   ssw = ssm[wv];
  const u32* hp = h1w + lane;
  for(int base = beg; base < end; base += CH){
    int cnt = end - base; if(cnt > CH) cnt = CH;
    #pragma unroll
    for(int k=0;k<CH;k+=8){
      int e = el + k;
      if(e < cnt){
        int s = csr[base+e];
        if(hh == 0) ssw[e] = s;
        float v = as1[s*8+hh] + advA;
        v = v > 0.f ? v : NEG*v;
        wsw[e*8+hh] = __expf(v);         // shift-invariant softmax; logits bounded
      }
    }
    int e = 0;
    for(; e+8 <= cnt; e += 8){
      int ss[8]; float ww[8]; u32 uu[8];
      #pragma unroll
      for(int j=0;j<8;j++){ ss[j] = ssw[e+j]; ww[j] = wsw[(e+j)*8+h]; }
      #pragma unroll
      for(int j=0;j<8;j++){ uu[j] = hp[(size_t)ss[j]*64]; }
      #pragma unroll
      for(int j=0;j<8;j++){
        den += ww[j];
        num0 = fmaf(ww[j], blo(uu[j]), num0);
        num1 = fmaf(ww[j], bhi(uu[j]), num1);
      }
    }
    for(; e+4 <= cnt; e += 4){
      int ss[4]; float ww[4]; u32 uu[4];
      #pragma unroll
      for(int j=0;j<4;j++){ ss[j] = ssw[e+j]; ww[j] = wsw[(e+j)*8+h]; }
      #pragma unroll
      for(int j=0;j<4;j++){ uu[j] = hp[(size_t)ss[j]*64]; }
      #pragma unroll
      for(int j=0;j<4;j++){
        den += ww[j];
        num0 = fmaf(ww[j], blo(uu[j]), num0);
        num1 = fmaf(ww[j], bhi(uu[j]), num1);
      }
    }
    for(; e < cnt; e++){
      int s = ssw[e];
      float w = wsw[e*8+h];
      u32 u = hp[(size_t)s*64];
      den += w;
      num0 = fmaf(w, blo(u), num0);
      num1 = fmaf(w, bhi(u), num1);
    }
  }
  float2 bb = ((const float2*)b1)[lane];
  float inv = 1.f / (den + 1e-16f);
  float r0 = num0*inv + bb.x;
  float r1 = num1*inv + bb.y;
  r0 = r0 > 0.f ? r0 : expm1f(r0);
  r1 = r1 > 0.f ? r1 : expm1f(r1);
  helu_w[(size_t)node*64 + lane] = (u32)f2bu(r0) | ((u32)f2bu(r1) << 16);
}

// ---------------- MFMA GEMM2: h2[N,16] = helu(bf16) @ W2 (split) + fused alpha2 ----------------
__global__ __launch_bounds__(256) void k_gemm2m(const u16* __restrict__ helu,
                                                const u16* __restrict__ w2th,
                                                const u16* __restrict__ w2tl,
                                                const float* __restrict__ Asv,
                                                const float* __restrict__ Adv,
                                                u16* __restrict__ h2b,
                                                float* __restrict__ as2,
                                                float* __restrict__ ad2){
  __shared__ u16 At[4][16][136];     // per-wave A tile
  __shared__ u16 Bh[16][136], Bl[16][136];
  int tid  = threadIdx.x;
  int wv   = tid >> 6;
  int lane = tid & 63;
  int fr = lane & 15, fg = lane >> 4;
  int row0 = blockIdx.x*64 + wv*16;

  {
    int r = tid >> 4, c8 = (tid & 15)*8;
    *(s8v*)&Bh[r][c8] = *(const s8v*)&w2th[r*128 + c8];
    *(s8v*)&Bl[r][c8] = *(const s8v*)&w2tl[r*128 + c8];
  }
  #pragma unroll
  for(int j=0;j<4;j++){
    int rl = j*4 + (lane >> 4);
    int rg = row0 + rl; if(rg >= N) rg = N-1;
    *(s8v*)&At[wv][rl][(lane & 15)*8] = *(const s8v*)&helu[(size_t)rg*128 + (lane & 15)*8];
  }
  __syncthreads();

  f4v acc = (f4v){0.f,0.f,0.f,0.f};
  #pragma unroll
  for(int kc=0; kc<4; kc++){
    int kk = kc*32 + fg*8;
    s8v a  = *(const s8v*)&At[wv][fr][kk];
    s8v bh = *(const s8v*)&Bh[fr][kk];
    s8v bl = *(const s8v*)&Bl[fr][kk];
    acc = __builtin_amdgcn_mfma_f32_16x16x32_bf16(a, bh, acc, 0,0,0);
    acc = __builtin_amdgcn_mfma_f32_16x16x32_bf16(a, bl, acc, 0,0,0);
  }
  float asv = Asv[fr], adv = Adv[fr];
  #pragma unroll
  for(int j=0;j<4;j++){
    int row = row0 + fg*4 + j;
    float ps = acc[j]*asv, pd = acc[j]*adv;
    ps += __shfl_xor(ps,1); ps += __shfl_xor(ps,2); ps += __shfl_xor(ps,4); ps += __shfl_xor(ps,8);
    pd += __shfl_xor(pd,1); pd += __shfl_xor(pd,2); pd += __shfl_xor(pd,4); pd += __shfl_xor(pd,8);
    if(row < N){
      h2b[(size_t)row*16 + fr] = f2bu(acc[j]);
      if(fr == 0){ as2[row] = ps; ad2[row] = pd; }
    }
  }
}

// ---------------- fused layer-2 aggregation: 8 lanes/node, batched loads ----------------
__global__ __launch_bounds__(256) void k_agg2(const int* __restrict__ off,
                                              const int* __restrict__ csr,
                                              const float* __restrict__ as2,
                                              const float* __restrict__ ad2,
                                              const u32* __restrict__ h2w,
                                              const float* __restrict__ b2,
                                              float* __restrict__ outp){
  int t = threadIdx.x;
  int node = blockIdx.x*32 + (t >> 3);
  int c2 = t & 7;                        // channels 2*c2, 2*c2+1
  if(node >= N) return;
  int beg = off[node], end = off[node+1];
  float adv = ad2[node];
  float den = 0.f, num0 = 0.f, num1 = 0.f;
  int gbase = t & 56;
  for(int base = beg; base < end; base += 8){
    int cnt = end - base; if(cnt > 8) cnt = 8;
    float w_my = 0.f; int s_my = 0;
    if(c2 < cnt){
      s_my = csr[base + c2];
      float v = as2[s_my] + adv;
      v = v > 0.f ? v : NEG*v;
      w_my = __expf(v);
    }
    float ww[8]; int ss[8]; u32 uu[8];
    #pragma unroll
    for(int j=0;j<8;j++){
      ww[j] = __shfl(w_my, gbase | j);
      ss[j] = __shfl(s_my, gbase | j);
    }
    #pragma unroll
    for(int j=0;j<8;j++){
      if(j < cnt) uu[j] = h2w[(size_t)ss[j]*8 + c2];
    }
    #pragma unroll
    for(int j=0;j<8;j++){
      if(j < cnt){
        den += ww[j];
        num0 = fmaf(ww[j], blo(uu[j]), num0);
        num1 = fmaf(ww[j], bhi(uu[j]), num1);
      }
    }
  }
  float inv = 1.f / (den + 1e-16f);
  float2 bb = ((const float2*)b2)[c2];
  float2 r;
  r.x = num0*inv + bb.x;
  r.y = num1*inv + bb.y;
  ((float2*)outp)[(size_t)node*8 + c2] = r;
}

extern "C" void kernel_launch(void* const* d_in, const int* in_sizes, int n_in,
                              void* d_out, int out_size, void* d_ws, size_t ws_size,
                              hipStream_t stream){
  const float* x     = (const float*)d_in[0];
  const int*   ei    = (const int*)  d_in[1];
  const float* W1    = (const float*)d_in[2];
  const float* av_s1 = (const float*)d_in[3];
  const float* av_d1 = (const float*)d_in[4];
  const float* b1    = (const float*)d_in[5];
  const float* W2    = (const float*)d_in[6];
  const float* av_s2 = (const float*)d_in[7];
  const float* av_d2 = (const float*)d_in[8];
  const float* b2    = (const float*)d_in[9];
  float* outp = (float*)d_out;

  char* p = (char*)d_ws;
  auto alloc = [&](size_t bytes){ char* q = p; p += (bytes + 255) & ~(size_t)255; return q; };
  u16*   h1b    = (u16*)  alloc((size_t)N*HH*2);
  u16*   helu_b = (u16*)  alloc((size_t)N*HH*2);
  u16*   h2b    = (u16*)  alloc((size_t)N*CLS*2);
  float* as1    = (float*)alloc((size_t)N*HEADS*4);
  float* ad1    = (float*)alloc((size_t)N*HEADS*4);
  float* as2    = (float*)alloc((size_t)N*4);
  float* ad2    = (float*)alloc((size_t)N*4);
  int*   deg    = (int*)  alloc((size_t)N*4);
  int*   head   = (int*)  alloc((size_t)N*4);
  int*   off    = (int*)  alloc((size_t)(N+1)*4);
  int*   csr    = (int*)  alloc((size_t)ETOT*4);
  u64*   nsrc   = (u64*)  alloc((size_t)ETOT*8);
  u16*   wth    = (u16*)  alloc((size_t)128*128*2);
  u16*   wtl    = (u16*)  alloc((size_t)128*128*2);
  u16*   w2th   = (u16*)  alloc((size_t)16*128*2);
  u16*   w2tl   = (u16*)  alloc((size_t)16*128*2);
  int*   bsum   = (int*)  alloc((size_t)NB*4);

  // custom head init (rocclr fillBuffer was 44 µs on the critical path)
  k_init<<<NB, 256, 0, stream>>>(head);

  // LDS-free: linked-list build (packed u64 nsrc) ∥ W pre-split
  k_linkprep<<<PREP_NB + LINK_NB, 256, 0, stream>>>(ei, head, nsrc,
                                                    W1, W2, wth, wtl, w2th, w2tl);

  // MFMA GEMM1 ∥ degree walk + block sums (walk hides under GEMM)
  k_gemm1walk<<<GEMM_NB + NB, 256, 0, stream>>>(x, wth, wtl, h1b, head, nsrc, deg, bsum);

  // CSR offsets + walk-fill (1 random line per edge) ∥ alpha1
  k_scan3alpha<<<NB + A1_NB, 256, 0, stream>>>(deg, bsum, head, nsrc, off, csr,
                                               h1b, av_s1, av_d1, as1, ad1);

  // layer 1 aggregation (1 wave/node — r14-proven config)
  k_agg1<<<N/4, 256, 0, stream>>>(off, csr, as1, ad1, (const u32*)h1b, b1, (u32*)helu_b);

  // layer 2
  k_gemm2m<<<(N+63)/64, 256, 0, stream>>>(helu_b, w2th, w2tl, av_s2, av_d2, h2b, as2, ad2);
  k_agg2<<<(N+31)/32, 256, 0, stream>>>(off, csr, as2, ad2, (const u32*)h2b, b2, outp);
}